// Round 5
// baseline (1294.320 us; speedup 1.0000x reference)
//
#include <hip/hip_runtime.h>
#include <hip/hip_bf16.h>

// GRNNTransformGated, round 4: operand-swapped MFMA + vectorized epilogues +
// LDS 48KB (3 blocks/CU) + fused small levels (j<=8) with device atomic grid
// barrier.
// Key trick: compute D = W @ hhu^T (weights as A-operand, activations as
// B-operand). A- and B-fragments of mfma_f32_16x16x32_bf16 have the SAME
// lane->element map (m/n=lane&15, k=(lane>>4)*8+j), so the round-3 packed
// buffers are reused verbatim with swapped mfma args. C-layout then gives
// each lane 4 CONSECUTIVE output columns of ONE row -> all epilogues
// (sigmoid*hhu, relu, softmax-gate) use b64 vector LDS ops and 8B global
// stores instead of scalar b16 ops.

#define H 64
#define F 7

typedef __bf16 bf16x8 __attribute__((ext_vector_type(8)));
typedef float f32x4 __attribute__((ext_vector_type(4)));
typedef unsigned short bfr;   // raw bf16 bits

__device__ __forceinline__ float bfr2f(bfr v) { return __uint_as_float(((unsigned)v) << 16); }
__device__ __forceinline__ bfr f2bfr(float f) {
    __hip_bfloat16 h = __float2bfloat16(f);
    return __builtin_bit_cast(bfr, h);
}

// fragment-order address (elements): frag (Mt,kt), lane (ln,q), 8 elems
__device__ __forceinline__ int fidx(int Mt, int kt, int q, int ln, int KT) {
    return ((((Mt * KT + kt) * 4 + q) * 16 + ln) * 8);
}

// pack weight matrix (N x K f32 row-major) into fragment order bf16
__device__ __forceinline__ void pack_one(const float* __restrict__ W, bfr* __restrict__ dst,
                                         int d, int K) {
    int KT = K >> 5;
    int j = d & 7, lnc = (d >> 3) & 15, q = (d >> 7) & 3;
    int t1 = d >> 9;
    int kt = t1 % KT, ntile = t1 / KT;
    int ncol = ntile * 16 + lnc;
    int k = kt * 32 + q * 8 + j;
    dst[d] = f2bfr(W[(size_t)ncol * K + k]);
}

__global__ void convert_weights(const float* __restrict__ Wr, const float* __restrict__ Wh,
                                const float* __restrict__ Wz,
                                bfr* __restrict__ wr, bfr* __restrict__ wh, bfr* __restrict__ wz) {
    int i = blockIdx.x * 256 + threadIdx.x;   // grid covers 65536
    if (i < 36864) pack_one(Wr, wr, i, 192);
    if (i < 12288) pack_one(Wh, wh, i, 192);
    if (i < 65536) pack_one(Wz, wz, i, 256);
}

// u for level 12: thread -> (row, 8-output octet); W_u octet rows are 56
// contiguous floats -> 14 float4 loads; one uint4 store (row-major u12).
__global__ void u12_kernel(const float* __restrict__ contents12,
                           const float* __restrict__ W_u, const float* __restrict__ b_u,
                           bfr* __restrict__ u12) {
    int t = blockIdx.x * 256 + threadIdx.x;
    int row = t >> 3, o0 = (t & 7) * 8;
    float wv[56];
#pragma unroll
    for (int p = 0; p < 14; ++p)
        *(float4*)&wv[p * 4] = *(const float4*)&W_u[o0 * 7 + p * 4];
    float c[7];
    const float* cp = contents12 + (size_t)row * 7;
#pragma unroll
    for (int k = 0; k < 7; ++k) c[k] = cp[k];
    ushort tmp[8];
#pragma unroll
    for (int jj = 0; jj < 8; ++jj) {
        float acc = b_u[o0 + jj];
#pragma unroll
        for (int k = 0; k < 7; ++k) acc += c[k] * wv[jj * 7 + k];
        tmp[jj] = f2bfr(fmaxf(acc, 0.f));
    }
    *(uint4*)&u12[(size_t)row * 64 + o0] = *(const uint4*)tmp;
}

__device__ __forceinline__ void process_tile(
    int tile,
    const float* __restrict__ contents_lvl,
    const float* __restrict__ W_u, const float* __restrict__ b_u,
    const bfr* __restrict__ up_prev,
    const bfr* __restrict__ wr, const float* __restrict__ b_r,
    const bfr* __restrict__ wh, const float* __restrict__ b_h,
    const bfr* __restrict__ wz, const float* __restrict__ b_z,
    bfr* __restrict__ up_cur, float* __restrict__ out,
    bfr* s_hhu, bfr* s_t)
{
    bfr* s_hH = s_t;   // aliased; h_H written only after all s_t reads done
    const int tid = threadIdx.x;
    const int lane = tid & 63, w = tid >> 6;
    const int ln = lane & 15, q = lane >> 4;
    const size_t r0 = (size_t)tile * 64;

    // ---- stage h_L,h_R (k=0..127) in fragment order ----
#pragma unroll
    for (int it = 0; it < 4; ++it) {
        int idx = it * 256 + tid;
        int lns = idx & 15, qs = (idx >> 4) & 3, kts = (idx >> 6) & 3, Mts = idx >> 8;
        int row = Mts * 16 + lns, k = kts * 32 + qs * 8;
        const bfr* src = (k < 64)
            ? up_prev + (size_t)(2 * (r0 + row)) * 64 + k
            : up_prev + (size_t)(2 * (r0 + row) + 1) * 64 + (k - 64);
        *(uint4*)&s_hhu[fidx(Mts, kts, qs, lns, 6)] = *(const uint4*)src;
    }
    // ---- u in-place (k=128..191), vectorized W_u loads ----
#pragma unroll
    for (int it = 0; it < 2; ++it) {
        int idx = it * 256 + tid;
        int lns = idx & 15, qs = (idx >> 4) & 3, ktl = (idx >> 6) & 1, Mts = (idx >> 7) & 3;
        int row = Mts * 16 + lns, o0 = ktl * 32 + qs * 8;
        float wv[56];
#pragma unroll
        for (int p = 0; p < 14; ++p)
            *(float4*)&wv[p * 4] = *(const float4*)&W_u[o0 * 7 + p * 4];
        float c[7];
        const float* cp = contents_lvl + (r0 + row) * 7;
#pragma unroll
        for (int k = 0; k < 7; ++k) c[k] = cp[k];
        ushort tmp[8];
#pragma unroll
        for (int jj = 0; jj < 8; ++jj) {
            float acc = b_u[o0 + jj];
#pragma unroll
            for (int k = 0; k < 7; ++k) acc += c[k] * wv[jj * 7 + k];
            tmp[jj] = f2bfr(fmaxf(acc, 0.f));
        }
        *(uint4*)&s_hhu[fidx(Mts, 4 + ktl, qs, lns, 6)] = *(const uint4*)tmp;
    }
    __syncthreads();

    // ---- mm1: D = W_r @ hhu^T -> lane holds R[row=ln][4 consec ncols] ----
#pragma unroll
    for (int nt = 0; nt < 3; ++nt) {
        int ntile = w * 3 + nt;
        bf16x8 Af[6];
#pragma unroll
        for (int kt = 0; kt < 6; ++kt)
            Af[kt] = *(const bf16x8*)&wr[fidx(ntile, kt, q, ln, 6)];
        int colbase = ntile * 16 + q * 4;
        f32x4 br4 = *(const f32x4*)&b_r[colbase];
#pragma unroll
        for (int Mt = 0; Mt < 4; ++Mt) {
            f32x4 acc = {0.f, 0.f, 0.f, 0.f};
#pragma unroll
            for (int kt = 0; kt < 6; ++kt) {
                bf16x8 Bf = *(const bf16x8*)&s_hhu[fidx(Mt, kt, q, ln, 6)];
                acc = __builtin_amdgcn_mfma_f32_16x16x32_bf16(Af[kt], Bf, acc, 0, 0, 0);
            }
            int addr = fidx(Mt, colbase >> 5, (colbase >> 3) & 3, ln, 6) + (colbase & 7);
            ushort hh[4], tt[4];
            *(uint2*)hh = *(const uint2*)&s_hhu[addr];
#pragma unroll
            for (int r = 0; r < 4; ++r) {
                float sg = 1.f / (1.f + __expf(-(acc[r] + br4[r])));
                tt[r] = f2bfr(sg * bfr2f(hh[r]));
            }
            *(uint2*)&s_t[addr] = *(const uint2*)tt;
        }
    }
    __syncthreads();

    // ---- mm2: D = W_h @ t^T (accumulate to regs), then store h_H ----
    f32x4 hacc[4];
    {
        bf16x8 Ah[6];
#pragma unroll
        for (int kt = 0; kt < 6; ++kt)
            Ah[kt] = *(const bf16x8*)&wh[fidx(w, kt, q, ln, 6)];
#pragma unroll
        for (int Mt = 0; Mt < 4; ++Mt) {
            f32x4 acc = {0.f, 0.f, 0.f, 0.f};
#pragma unroll
            for (int kt = 0; kt < 6; ++kt) {
                bf16x8 Bf = *(const bf16x8*)&s_t[fidx(Mt, kt, q, ln, 6)];
                acc = __builtin_amdgcn_mfma_f32_16x16x32_bf16(Ah[kt], Bf, acc, 0, 0, 0);
            }
            hacc[Mt] = acc;
        }
    }
    __syncthreads();   // all s_t reads complete -> safe to overwrite (aliased s_hH)
    {
        int colbase = w * 16 + q * 4;
        f32x4 bh4 = *(const f32x4*)&b_h[colbase];
#pragma unroll
        for (int Mt = 0; Mt < 4; ++Mt) {
            int addr = fidx(Mt, colbase >> 5, (colbase >> 3) & 3, ln, 2) + (colbase & 7);
            ushort hv[4];
#pragma unroll
            for (int r = 0; r < 4; ++r) hv[r] = f2bfr(fmaxf(hacc[Mt][r] + bh4[r], 0.f));
            *(uint2*)&s_hH[addr] = *(const uint2*)hv;
        }
    }
    __syncthreads();

    // ---- mm3: D = W_z @ [h_H,hhu]^T ; lane holds all 4 z-groups for its
    //      (row=ln, 4 consec h-cols) -> softmax+gate in registers ----
    {
        f32x4 az[4][4];
#pragma unroll
        for (int Mt = 0; Mt < 4; ++Mt)
#pragma unroll
            for (int g = 0; g < 4; ++g) az[Mt][g] = (f32x4){0.f, 0.f, 0.f, 0.f};
#pragma unroll
        for (int g = 0; g < 4; ++g) {
            int ntile = g * 4 + w;
            bf16x8 Aw[8];
#pragma unroll
            for (int kt = 0; kt < 8; ++kt)
                Aw[kt] = *(const bf16x8*)&wz[fidx(ntile, kt, q, ln, 8)];
#pragma unroll
            for (int Mt = 0; Mt < 4; ++Mt) {
                f32x4 acc = az[Mt][g];
                acc = __builtin_amdgcn_mfma_f32_16x16x32_bf16(
                    Aw[0], *(const bf16x8*)&s_hH[fidx(Mt, 0, q, ln, 2)], acc, 0, 0, 0);
                acc = __builtin_amdgcn_mfma_f32_16x16x32_bf16(
                    Aw[1], *(const bf16x8*)&s_hH[fidx(Mt, 1, q, ln, 2)], acc, 0, 0, 0);
#pragma unroll
                for (int kt = 0; kt < 6; ++kt)
                    acc = __builtin_amdgcn_mfma_f32_16x16x32_bf16(
                        Aw[2 + kt], *(const bf16x8*)&s_hhu[fidx(Mt, kt, q, ln, 6)], acc, 0, 0, 0);
                az[Mt][g] = acc;
            }
        }
        int colbase = w * 16 + q * 4;
        f32x4 bz0 = *(const f32x4*)&b_z[colbase];
        f32x4 bz1 = *(const f32x4*)&b_z[64 + colbase];
        f32x4 bz2 = *(const f32x4*)&b_z[128 + colbase];
        f32x4 bz3 = *(const f32x4*)&b_z[192 + colbase];
#pragma unroll
        for (int Mt = 0; Mt < 4; ++Mt) {
            int aH = fidx(Mt, colbase >> 5, (colbase >> 3) & 3, ln, 2) + (colbase & 7);
            int a0 = fidx(Mt, colbase >> 5, (colbase >> 3) & 3, ln, 6) + (colbase & 7);
            int c1 = 64 + colbase, c2 = 128 + colbase;
            int a1 = fidx(Mt, c1 >> 5, (c1 >> 3) & 3, ln, 6) + (c1 & 7);
            int a2 = fidx(Mt, c2 >> 5, (c2 >> 3) & 3, ln, 6) + (c2 & 7);
            ushort hHv[4], u0[4], u1[4], u2[4];
            *(uint2*)hHv = *(const uint2*)&s_hH[aH];
            *(uint2*)u0 = *(const uint2*)&s_hhu[a0];
            *(uint2*)u1 = *(const uint2*)&s_hhu[a1];
            *(uint2*)u2 = *(const uint2*)&s_hhu[a2];
            ushort ov[4]; float of[4];
#pragma unroll
            for (int r = 0; r < 4; ++r) {
                float z0 = az[Mt][0][r] + bz0[r];
                float z1 = az[Mt][1][r] + bz1[r];
                float z2 = az[Mt][2][r] + bz2[r];
                float z3 = az[Mt][3][r] + bz3[r];
                float m = fmaxf(fmaxf(z0, z1), fmaxf(z2, z3));
                float e0 = __expf(z0 - m), e1 = __expf(z1 - m);
                float e2 = __expf(z2 - m), e3 = __expf(z3 - m);
                float inv = 1.f / (e0 + e1 + e2 + e3);
                float v = (e0 * bfr2f(hHv[r]) + e1 * bfr2f(u0[r]) +
                           e2 * bfr2f(u1[r]) + e3 * bfr2f(u2[r])) * inv;
                ov[r] = f2bfr(v); of[r] = v;
            }
            size_t row = r0 + Mt * 16 + ln;
            *(uint2*)&up_cur[row * 64 + colbase] = *(const uint2*)ov;
            if (out) *(float4*)&out[row * 64 + colbase] = *(const float4*)of;
        }
    }
}

__global__ __launch_bounds__(256, 3) void level_kernel(
    const float* __restrict__ contents_lvl,
    const float* __restrict__ W_u, const float* __restrict__ b_u,
    const bfr* __restrict__ up_prev,
    const bfr* __restrict__ wr, const float* __restrict__ b_r,
    const bfr* __restrict__ wh, const float* __restrict__ b_h,
    const bfr* __restrict__ wz, const float* __restrict__ b_z,
    bfr* __restrict__ up_cur)
{
    __shared__ bfr s_hhu[12288];
    __shared__ bfr s_t[12288];
    process_tile(blockIdx.x, contents_lvl, W_u, b_u, up_prev,
                 wr, b_r, wh, b_h, wz, b_z, up_cur, nullptr, s_hhu, s_t);
}

// monotonic device-scope grid barrier (256 blocks <= 256 CUs -> co-resident)
__device__ __forceinline__ void grid_barrier(unsigned* ctr, unsigned target) {
    __syncthreads();
    if (threadIdx.x == 0) {
        __threadfence();
        __hip_atomic_fetch_add(ctr, 1u, __ATOMIC_RELEASE, __HIP_MEMORY_SCOPE_AGENT);
        while (__hip_atomic_load(ctr, __ATOMIC_ACQUIRE, __HIP_MEMORY_SCOPE_AGENT) < target)
            __builtin_amdgcn_s_sleep(4);
    }
    __syncthreads();
}

__global__ __launch_bounds__(256, 3) void fused_small(
    const float* __restrict__ contents,
    const float* __restrict__ W_u, const float* __restrict__ b_u,
    const bfr* __restrict__ wr, const float* __restrict__ b_r,
    const bfr* __restrict__ wh, const float* __restrict__ b_h,
    const bfr* __restrict__ wz, const float* __restrict__ b_z,
    bfr* __restrict__ buf_odd, bfr* __restrict__ buf_even,
    float* __restrict__ out, unsigned* __restrict__ ctr)
{
    __shared__ bfr s_hhu[12288];
    __shared__ bfr s_t[12288];
    unsigned epoch = 0;
    for (int j = 8; j >= 0; --j) {
        int ntiles = 1 << j;
        const bfr* up_prev = (j & 1) ? buf_even : buf_odd;
        bfr* up_cur = (j & 1) ? buf_odd : buf_even;
        const float* cl = contents + (size_t)64 * ((1 << j) - 1) * 7;
        if ((int)blockIdx.x < ntiles)
            process_tile(blockIdx.x, cl, W_u, b_u, up_prev, wr, b_r, wh, b_h,
                         wz, b_z, up_cur, (j == 0) ? out : nullptr, s_hhu, s_t);
        if (j > 0) { ++epoch; grid_barrier(ctr, 256u * epoch); }
    }
}

extern "C" void kernel_launch(void* const* d_in, const int* in_sizes, int n_in,
                              void* d_out, int out_size, void* d_ws, size_t ws_size,
                              hipStream_t stream) {
    const float* contents = (const float*)d_in[0];
    const float* W_u = (const float*)d_in[1];
    const float* b_u = (const float*)d_in[2];
    const float* W_r = (const float*)d_in[3];
    const float* b_r = (const float*)d_in[4];
    const float* W_h = (const float*)d_in[5];
    const float* b_h = (const float*)d_in[6];
    const float* W_z = (const float*)d_in[7];
    const float* b_z = (const float*)d_in[8];
    float* out = (float*)d_out;

    // ws layout (bf16 bits): u12 | buf_odd | buf_even | wr | wh | wz | ctr
    bfr* u12 = (bfr*)d_ws;                                  // 262144*64
    bfr* buf_odd = u12 + (size_t)262144 * 64;               // 131072*64
    bfr* buf_even = buf_odd + (size_t)131072 * 64;          // 65536*64
    bfr* wr = buf_even + (size_t)65536 * 64;                // 36864
    bfr* wh = wr + 36864;                                   // 12288
    bfr* wz = wh + 12288;                                   // 65536
    unsigned* ctr = (unsigned*)(wz + 65536);

    hipMemsetAsync(ctr, 0, sizeof(unsigned), stream);
    convert_weights<<<256, 256, 0, stream>>>(W_r, W_h, W_z, wr, wh, wz);

    const size_t OFF12 = (size_t)64 * 4095;   // rows before level 12
    u12_kernel<<<8192, 256, 0, stream>>>(contents + OFF12 * 7, W_u, b_u, u12);

    // big levels: one tile per block
    const size_t OFF11 = (size_t)64 * 2047, OFF10 = (size_t)64 * 1023, OFF9 = (size_t)64 * 511;
    level_kernel<<<2048, 256, 0, stream>>>(contents + OFF11 * 7, W_u, b_u, u12,
                                           wr, b_r, wh, b_h, wz, b_z, buf_odd);
    level_kernel<<<1024, 256, 0, stream>>>(contents + OFF10 * 7, W_u, b_u, buf_odd,
                                           wr, b_r, wh, b_h, wz, b_z, buf_even);
    level_kernel<<<512, 256, 0, stream>>>(contents + OFF9 * 7, W_u, b_u, buf_even,
                                          wr, b_r, wh, b_h, wz, b_z, buf_odd);
    // levels 8..0 fused with grid barrier
    fused_small<<<256, 256, 0, stream>>>(contents, W_u, b_u, wr, b_r, wh, b_h,
                                         wz, b_z, buf_odd, buf_even, out, ctr);
}

// Round 6
// 354.285 us; speedup vs baseline: 3.6533x; 3.6533x over previous
//
#include <hip/hip_runtime.h>
#include <hip/hip_bf16.h>

// GRNNTransformGated, round 5: round-4 tile pipeline (operand-swapped MFMA,
// vectorized b64 epilogues, 48KB LDS -> 3 blocks/CU) with the round-3 launch
// structure: ONE KERNEL PER LEVEL, no grid barriers.
// Round-4 post-mortem: agent-scope spin barriers cost ~137us EACH on MI355X
// (acquire-poll emits L2 invalidates, release emits L2 writebacks -> cross-XCD
// flush storm; fused_small ran at 0.3% MfmaUtil). Kernel launches are ~2-5us;
// de-fusion is strictly better.
// Key layout trick (round 4): compute D = W @ hhu^T (weights as A-operand).
// A- and B-fragments of mfma_f32_16x16x32_bf16 share the same lane->element
// map, so one packed buffer serves both roles; C-layout gives each lane 4
// consecutive output columns of one row -> all epilogues are b64 LDS ops and
// 8B global stores.

#define H 64
#define F 7

typedef __bf16 bf16x8 __attribute__((ext_vector_type(8)));
typedef float f32x4 __attribute__((ext_vector_type(4)));
typedef unsigned short bfr;   // raw bf16 bits

__device__ __forceinline__ float bfr2f(bfr v) { return __uint_as_float(((unsigned)v) << 16); }
__device__ __forceinline__ bfr f2bfr(float f) {
    __hip_bfloat16 h = __float2bfloat16(f);
    return __builtin_bit_cast(bfr, h);
}

// fragment-order address (elements): frag (Mt,kt), lane (ln,q), 8 elems
__device__ __forceinline__ int fidx(int Mt, int kt, int q, int ln, int KT) {
    return ((((Mt * KT + kt) * 4 + q) * 16 + ln) * 8);
}

// pack weight matrix (N x K f32 row-major) into fragment order bf16
__device__ __forceinline__ void pack_one(const float* __restrict__ W, bfr* __restrict__ dst,
                                         int d, int K) {
    int KT = K >> 5;
    int j = d & 7, lnc = (d >> 3) & 15, q = (d >> 7) & 3;
    int t1 = d >> 9;
    int kt = t1 % KT, ntile = t1 / KT;
    int ncol = ntile * 16 + lnc;
    int k = kt * 32 + q * 8 + j;
    dst[d] = f2bfr(W[(size_t)ncol * K + k]);
}

__global__ void convert_weights(const float* __restrict__ Wr, const float* __restrict__ Wh,
                                const float* __restrict__ Wz,
                                bfr* __restrict__ wr, bfr* __restrict__ wh, bfr* __restrict__ wz) {
    int i = blockIdx.x * 256 + threadIdx.x;   // grid covers 65536
    if (i < 36864) pack_one(Wr, wr, i, 192);
    if (i < 12288) pack_one(Wh, wh, i, 192);
    if (i < 65536) pack_one(Wz, wz, i, 256);
}

// u for level 12: thread -> (row, 8-output octet); W_u octet rows are 56
// contiguous floats -> 14 float4 loads; one uint4 store (row-major u12).
__global__ void u12_kernel(const float* __restrict__ contents12,
                           const float* __restrict__ W_u, const float* __restrict__ b_u,
                           bfr* __restrict__ u12) {
    int t = blockIdx.x * 256 + threadIdx.x;
    int row = t >> 3, o0 = (t & 7) * 8;
    float wv[56];
#pragma unroll
    for (int p = 0; p < 14; ++p)
        *(float4*)&wv[p * 4] = *(const float4*)&W_u[o0 * 7 + p * 4];
    float c[7];
    const float* cp = contents12 + (size_t)row * 7;
#pragma unroll
    for (int k = 0; k < 7; ++k) c[k] = cp[k];
    ushort tmp[8];
#pragma unroll
    for (int jj = 0; jj < 8; ++jj) {
        float acc = b_u[o0 + jj];
#pragma unroll
        for (int k = 0; k < 7; ++k) acc += c[k] * wv[jj * 7 + k];
        tmp[jj] = f2bfr(fmaxf(acc, 0.f));
    }
    *(uint4*)&u12[(size_t)row * 64 + o0] = *(const uint4*)tmp;
}

__device__ __forceinline__ void process_tile(
    int tile,
    const float* __restrict__ contents_lvl,
    const float* __restrict__ W_u, const float* __restrict__ b_u,
    const bfr* __restrict__ up_prev,
    const bfr* __restrict__ wr, const float* __restrict__ b_r,
    const bfr* __restrict__ wh, const float* __restrict__ b_h,
    const bfr* __restrict__ wz, const float* __restrict__ b_z,
    bfr* __restrict__ up_cur, float* __restrict__ out,
    bfr* s_hhu, bfr* s_t)
{
    bfr* s_hH = s_t;   // aliased; h_H written only after all s_t reads done
    const int tid = threadIdx.x;
    const int lane = tid & 63, w = tid >> 6;
    const int ln = lane & 15, q = lane >> 4;
    const size_t r0 = (size_t)tile * 64;

    // ---- stage h_L,h_R (k=0..127) in fragment order ----
#pragma unroll
    for (int it = 0; it < 4; ++it) {
        int idx = it * 256 + tid;
        int lns = idx & 15, qs = (idx >> 4) & 3, kts = (idx >> 6) & 3, Mts = idx >> 8;
        int row = Mts * 16 + lns, k = kts * 32 + qs * 8;
        const bfr* src = (k < 64)
            ? up_prev + (size_t)(2 * (r0 + row)) * 64 + k
            : up_prev + (size_t)(2 * (r0 + row) + 1) * 64 + (k - 64);
        *(uint4*)&s_hhu[fidx(Mts, kts, qs, lns, 6)] = *(const uint4*)src;
    }
    // ---- u in-place (k=128..191), vectorized W_u loads ----
#pragma unroll
    for (int it = 0; it < 2; ++it) {
        int idx = it * 256 + tid;
        int lns = idx & 15, qs = (idx >> 4) & 3, ktl = (idx >> 6) & 1, Mts = (idx >> 7) & 3;
        int row = Mts * 16 + lns, o0 = ktl * 32 + qs * 8;
        float wv[56];
#pragma unroll
        for (int p = 0; p < 14; ++p)
            *(float4*)&wv[p * 4] = *(const float4*)&W_u[o0 * 7 + p * 4];
        float c[7];
        const float* cp = contents_lvl + (r0 + row) * 7;
#pragma unroll
        for (int k = 0; k < 7; ++k) c[k] = cp[k];
        ushort tmp[8];
#pragma unroll
        for (int jj = 0; jj < 8; ++jj) {
            float acc = b_u[o0 + jj];
#pragma unroll
            for (int k = 0; k < 7; ++k) acc += c[k] * wv[jj * 7 + k];
            tmp[jj] = f2bfr(fmaxf(acc, 0.f));
        }
        *(uint4*)&s_hhu[fidx(Mts, 4 + ktl, qs, lns, 6)] = *(const uint4*)tmp;
    }
    __syncthreads();

    // ---- mm1: D = W_r @ hhu^T -> lane holds R[row=ln][4 consec ncols] ----
#pragma unroll
    for (int nt = 0; nt < 3; ++nt) {
        int ntile = w * 3 + nt;
        bf16x8 Af[6];
#pragma unroll
        for (int kt = 0; kt < 6; ++kt)
            Af[kt] = *(const bf16x8*)&wr[fidx(ntile, kt, q, ln, 6)];
        int colbase = ntile * 16 + q * 4;
        f32x4 br4 = *(const f32x4*)&b_r[colbase];
#pragma unroll
        for (int Mt = 0; Mt < 4; ++Mt) {
            f32x4 acc = {0.f, 0.f, 0.f, 0.f};
#pragma unroll
            for (int kt = 0; kt < 6; ++kt) {
                bf16x8 Bf = *(const bf16x8*)&s_hhu[fidx(Mt, kt, q, ln, 6)];
                acc = __builtin_amdgcn_mfma_f32_16x16x32_bf16(Af[kt], Bf, acc, 0, 0, 0);
            }
            int addr = fidx(Mt, colbase >> 5, (colbase >> 3) & 3, ln, 6) + (colbase & 7);
            ushort hh[4], tt[4];
            *(uint2*)hh = *(const uint2*)&s_hhu[addr];
#pragma unroll
            for (int r = 0; r < 4; ++r) {
                float sg = 1.f / (1.f + __expf(-(acc[r] + br4[r])));
                tt[r] = f2bfr(sg * bfr2f(hh[r]));
            }
            *(uint2*)&s_t[addr] = *(const uint2*)tt;
        }
    }
    __syncthreads();

    // ---- mm2: D = W_h @ t^T (accumulate to regs), then store h_H ----
    f32x4 hacc[4];
    {
        bf16x8 Ah[6];
#pragma unroll
        for (int kt = 0; kt < 6; ++kt)
            Ah[kt] = *(const bf16x8*)&wh[fidx(w, kt, q, ln, 6)];
#pragma unroll
        for (int Mt = 0; Mt < 4; ++Mt) {
            f32x4 acc = {0.f, 0.f, 0.f, 0.f};
#pragma unroll
            for (int kt = 0; kt < 6; ++kt) {
                bf16x8 Bf = *(const bf16x8*)&s_t[fidx(Mt, kt, q, ln, 6)];
                acc = __builtin_amdgcn_mfma_f32_16x16x32_bf16(Ah[kt], Bf, acc, 0, 0, 0);
            }
            hacc[Mt] = acc;
        }
    }
    __syncthreads();   // all s_t reads complete -> safe to overwrite (aliased s_hH)
    {
        int colbase = w * 16 + q * 4;
        f32x4 bh4 = *(const f32x4*)&b_h[colbase];
#pragma unroll
        for (int Mt = 0; Mt < 4; ++Mt) {
            int addr = fidx(Mt, colbase >> 5, (colbase >> 3) & 3, ln, 2) + (colbase & 7);
            ushort hv[4];
#pragma unroll
            for (int r = 0; r < 4; ++r) hv[r] = f2bfr(fmaxf(hacc[Mt][r] + bh4[r], 0.f));
            *(uint2*)&s_hH[addr] = *(const uint2*)hv;
        }
    }
    __syncthreads();

    // ---- mm3: D = W_z @ [h_H,hhu]^T ; lane holds all 4 z-groups for its
    //      (row=ln, 4 consec h-cols) -> softmax+gate in registers ----
    {
        f32x4 az[4][4];
#pragma unroll
        for (int Mt = 0; Mt < 4; ++Mt)
#pragma unroll
            for (int g = 0; g < 4; ++g) az[Mt][g] = (f32x4){0.f, 0.f, 0.f, 0.f};
#pragma unroll
        for (int g = 0; g < 4; ++g) {
            int ntile = g * 4 + w;
            bf16x8 Aw[8];
#pragma unroll
            for (int kt = 0; kt < 8; ++kt)
                Aw[kt] = *(const bf16x8*)&wz[fidx(ntile, kt, q, ln, 8)];
#pragma unroll
            for (int Mt = 0; Mt < 4; ++Mt) {
                f32x4 acc = az[Mt][g];
                acc = __builtin_amdgcn_mfma_f32_16x16x32_bf16(
                    Aw[0], *(const bf16x8*)&s_hH[fidx(Mt, 0, q, ln, 2)], acc, 0, 0, 0);
                acc = __builtin_amdgcn_mfma_f32_16x16x32_bf16(
                    Aw[1], *(const bf16x8*)&s_hH[fidx(Mt, 1, q, ln, 2)], acc, 0, 0, 0);
#pragma unroll
                for (int kt = 0; kt < 6; ++kt)
                    acc = __builtin_amdgcn_mfma_f32_16x16x32_bf16(
                        Aw[2 + kt], *(const bf16x8*)&s_hhu[fidx(Mt, kt, q, ln, 6)], acc, 0, 0, 0);
                az[Mt][g] = acc;
            }
        }
        int colbase = w * 16 + q * 4;
        f32x4 bz0 = *(const f32x4*)&b_z[colbase];
        f32x4 bz1 = *(const f32x4*)&b_z[64 + colbase];
        f32x4 bz2 = *(const f32x4*)&b_z[128 + colbase];
        f32x4 bz3 = *(const f32x4*)&b_z[192 + colbase];
#pragma unroll
        for (int Mt = 0; Mt < 4; ++Mt) {
            int aH = fidx(Mt, colbase >> 5, (colbase >> 3) & 3, ln, 2) + (colbase & 7);
            int a0 = fidx(Mt, colbase >> 5, (colbase >> 3) & 3, ln, 6) + (colbase & 7);
            int c1 = 64 + colbase, c2 = 128 + colbase;
            int a1 = fidx(Mt, c1 >> 5, (c1 >> 3) & 3, ln, 6) + (c1 & 7);
            int a2 = fidx(Mt, c2 >> 5, (c2 >> 3) & 3, ln, 6) + (c2 & 7);
            ushort hHv[4], u0[4], u1[4], u2[4];
            *(uint2*)hHv = *(const uint2*)&s_hH[aH];
            *(uint2*)u0 = *(const uint2*)&s_hhu[a0];
            *(uint2*)u1 = *(const uint2*)&s_hhu[a1];
            *(uint2*)u2 = *(const uint2*)&s_hhu[a2];
            ushort ov[4]; float of[4];
#pragma unroll
            for (int r = 0; r < 4; ++r) {
                float z0 = az[Mt][0][r] + bz0[r];
                float z1 = az[Mt][1][r] + bz1[r];
                float z2 = az[Mt][2][r] + bz2[r];
                float z3 = az[Mt][3][r] + bz3[r];
                float m = fmaxf(fmaxf(z0, z1), fmaxf(z2, z3));
                float e0 = __expf(z0 - m), e1 = __expf(z1 - m);
                float e2 = __expf(z2 - m), e3 = __expf(z3 - m);
                float inv = 1.f / (e0 + e1 + e2 + e3);
                float v = (e0 * bfr2f(hHv[r]) + e1 * bfr2f(u0[r]) +
                           e2 * bfr2f(u1[r]) + e3 * bfr2f(u2[r])) * inv;
                ov[r] = f2bfr(v); of[r] = v;
            }
            size_t row = r0 + Mt * 16 + ln;
            *(uint2*)&up_cur[row * 64 + colbase] = *(const uint2*)ov;
            if (out) *(float4*)&out[row * 64 + colbase] = *(const float4*)of;
        }
    }
}

__global__ __launch_bounds__(256, 3) void level_kernel(
    const float* __restrict__ contents_lvl,
    const float* __restrict__ W_u, const float* __restrict__ b_u,
    const bfr* __restrict__ up_prev,
    const bfr* __restrict__ wr, const float* __restrict__ b_r,
    const bfr* __restrict__ wh, const float* __restrict__ b_h,
    const bfr* __restrict__ wz, const float* __restrict__ b_z,
    bfr* __restrict__ up_cur, float* __restrict__ out)
{
    __shared__ bfr s_hhu[12288];
    __shared__ bfr s_t[12288];
    process_tile(blockIdx.x, contents_lvl, W_u, b_u, up_prev,
                 wr, b_r, wh, b_h, wz, b_z, up_cur, out, s_hhu, s_t);
}

extern "C" void kernel_launch(void* const* d_in, const int* in_sizes, int n_in,
                              void* d_out, int out_size, void* d_ws, size_t ws_size,
                              hipStream_t stream) {
    const float* contents = (const float*)d_in[0];
    const float* W_u = (const float*)d_in[1];
    const float* b_u = (const float*)d_in[2];
    const float* W_r = (const float*)d_in[3];
    const float* b_r = (const float*)d_in[4];
    const float* W_h = (const float*)d_in[5];
    const float* b_h = (const float*)d_in[6];
    const float* W_z = (const float*)d_in[7];
    const float* b_z = (const float*)d_in[8];
    float* out = (float*)d_out;

    // ws layout (bf16 bits): u12 | buf_odd | buf_even | wr | wh | wz
    bfr* u12 = (bfr*)d_ws;                                  // 262144*64
    bfr* buf_odd = u12 + (size_t)262144 * 64;               // 131072*64
    bfr* buf_even = buf_odd + (size_t)131072 * 64;          // 65536*64
    bfr* wr = buf_even + (size_t)65536 * 64;                // 36864
    bfr* wh = wr + 36864;                                   // 12288
    bfr* wz = wh + 12288;                                   // 65536

    convert_weights<<<256, 256, 0, stream>>>(W_r, W_h, W_z, wr, wh, wz);

    const size_t OFF12 = (size_t)64 * 4095;   // rows before level 12
    u12_kernel<<<8192, 256, 0, stream>>>(contents + OFF12 * 7, W_u, b_u, u12);

    const bfr* up_prev = u12;
    for (int j = 11; j >= 0; --j) {
        int ntiles = 1 << j;                  // n_rows/64 = 2^j
        bfr* up_cur = (j & 1) ? buf_odd : buf_even;
        const float* cl = contents + (size_t)64 * ((1 << j) - 1) * 7;
        level_kernel<<<ntiles, 256, 0, stream>>>(
            cl, W_u, b_u, up_prev, wr, b_r, wh, b_h, wz, b_z,
            up_cur, (j == 0) ? out : nullptr);
        up_prev = up_cur;
    }
}